// Round 11
// baseline (132.786 us; speedup 1.0000x reference)
//
#include <hip/hip_runtime.h>
#include <math.h>

#define D      16384
#define D4     4096    // D/4
#define S      2048
#define NF     40
#define NFP    48      // padded flow count for MFMA (3 x 16)
#define ROWS   8
#define TPB    1024
#define CH4    256
#define CHUNK  1024
#define NCHUNK 16
#define KSPLIT 8       // K-splits in the MFMA GEMM

// ---- d_ws float offsets (fast path), ~7.2 MB total (ws measured 512 MB) ----
#define WW_OFF     0                        // WW[k][j] = w_j . w_k   (1600)
#define UW_OFF     1600                     // UW[k][j] = u_j . w_k   (1600)
#define COEF_OFF   3200                     // coef[j]                (40)
#define AT_OFF     4096                     // aT[S][NF] fp32         (81920)
#define WB_OFF     (AT_OFF + NF * S)        // Wb bf16 [NFP][D] as u32 (NFP*D/2 slots)
#define C0P_OFF    (WB_OFF + (NFP * D) / 2) // c0 partials [S][KSPLIT][NF]  (655360)
#define UH_OFF     (C0P_OFF + S * KSPLIT * NF) // uhat fp32 [NF][D] (dedicated region)
#define WS_NEED    (UH_OFF + NF * D)

typedef __attribute__((ext_vector_type(8))) __bf16 bf16x8;
typedef __attribute__((ext_vector_type(4))) float  f32x4;
union FragU { unsigned u[4]; bf16x8 b; };

__device__ __forceinline__ float dot4(float4 a, float4 b) {
    return fmaf(a.x, b.x, fmaf(a.y, b.y, fmaf(a.z, b.z, a.w * b.w)));
}
__device__ __forceinline__ void fma4(float4& o, float a, float4 u) {
    o.x = fmaf(a, u.x, o.x); o.y = fmaf(a, u.y, o.y);
    o.z = fmaf(a, u.z, o.z); o.w = fmaf(a, u.w, o.w);
}
// fp32 -> bf16 (RNE) pair pack: returns (lo | hi<<16)
__device__ __forceinline__ unsigned bpack(float lo, float hi) {
    unsigned a = __float_as_uint(lo);
    unsigned b = __float_as_uint(hi);
    a += 0x7fffu + ((a >> 16) & 1u);
    b += 0x7fffu + ((b >> 16) & 1u);
    return (a >> 16) | (b & 0xffff0000u);
}

// ---------------------------------------------------------------------------
// P1: block (k, h), grid NFP*8 (fast) / NF*8 (fallback), TPB 512.
//   k<40: WW[k][j], UW[k][j] for j in [5h,5h+5); coef (local reduction);
//         if doWb: Wb bf16 slice h AND UH slice h = u + coef*w (reuses the
//         i==h W/U loads; zero extra global traffic).
//   k>=40: zero-pad Wb row slice.
// ---------------------------------------------------------------------------
__global__ __launch_bounds__(512) void pair_wb_kernel(const float* __restrict__ Wg,
                                                      const float* __restrict__ Ug,
                                                      float* __restrict__ tbl,
                                                      int doWb) {
    const int k = blockIdx.x >> 3;
    const int h = blockIdx.x & 7;
    const int t = threadIdx.x;
    uint2* Wb2 = (uint2*)((unsigned*)(tbl + WB_OFF) + (size_t)k * (D / 2));

    if (k >= NF) {                       // zero-pad rows 40..47 (fast path only)
        Wb2[h * 512 + t] = make_uint2(0u, 0u);
        return;
    }

    const int j0 = h * 5;
    const int wave = t >> 6, lane = t & 63;
    const float4* W4 = (const float4*)Wg;
    const float4* U4 = (const float4*)Ug;

    float ww[5], wu[5], wkk = 0.f, wku = 0.f;
    float4 wkSave, ukSave;
    #pragma unroll
    for (int j = 0; j < 5; ++j) { ww[j] = 0.f; wu[j] = 0.f; }

    for (int i = 0; i < 8; ++i) {
        const int pos = i * 512 + t;
        float4 wk = W4[(size_t)k * D4 + pos];
        float4 uk = U4[(size_t)k * D4 + pos];
        if (i == h) { wkSave = wk; ukSave = uk; }
        wkk += dot4(wk, wk);
        wku += dot4(wk, uk);
        #pragma unroll
        for (int j = 0; j < 5; ++j) {
            float4 wj = W4[(size_t)(j0 + j) * D4 + pos];
            float4 uj = U4[(size_t)(j0 + j) * D4 + pos];
            ww[j] += dot4(wk, wj);
            wu[j] += dot4(wk, uj);
        }
    }

    if (doWb) {
        uint2 p;
        p.x = bpack(wkSave.x, wkSave.y);
        p.y = bpack(wkSave.z, wkSave.w);
        Wb2[h * 512 + t] = p;
    }

    float v[12];
    #pragma unroll
    for (int j = 0; j < 5; ++j) { v[j] = ww[j]; v[5 + j] = wu[j]; }
    v[10] = wkk; v[11] = wku;
    #pragma unroll
    for (int e = 0; e < 12; ++e) {
        #pragma unroll
        for (int off = 32; off >= 1; off >>= 1) v[e] += __shfl_xor(v[e], off);
    }

    __shared__ float red[8][12];
    __shared__ float fin[12];
    __shared__ float coefL;
    if (lane == 0) {
        #pragma unroll
        for (int e = 0; e < 12; ++e) red[wave][e] = v[e];
    }
    __syncthreads();
    if (t < 12) {
        float s = 0.f;
        #pragma unroll
        for (int w = 0; w < 8; ++w) s += red[w][t];
        fin[t] = s;
        if (t < 5)       tbl[WW_OFF + k * NF + j0 + t] = s;
        else if (t < 10) tbl[UW_OFF + k * NF + j0 + (t - 5)] = s;
    }
    __syncthreads();
    if (t == 0) {
        float wwd = fin[10], wud = fin[11];
        float sp = (wud > 0.f) ? (wud + log1pf(expf(-wud))) : log1pf(expf(wud));
        float cf = ((-1.f + sp) - wud) / wwd;
        coefL = cf;
        if (h == 0) tbl[COEF_OFF + k] = cf;
    }
    __syncthreads();

    if (doWb) {   // UH slice h, from the saved i==h values
        const float cf = coefL;
        float4 r;
        r.x = fmaf(cf, wkSave.x, ukSave.x);
        r.y = fmaf(cf, wkSave.y, ukSave.y);
        r.z = fmaf(cf, wkSave.z, ukSave.z);
        r.w = fmaf(cf, wkSave.w, ukSave.w);
        ((float4*)(tbl + UH_OFF))[(size_t)k * D4 + h * 512 + t] = r;
    }
}

// ---------------------------------------------------------------------------
// G: MFMA partial GEMM. grid = 128 row-tiles x KSPLIT=8 -> 1024 blocks,
// TPB 256 (4 waves). Unchanged (proven, ~HBM-bound on X).
// ---------------------------------------------------------------------------
__global__ __launch_bounds__(256) void gemm_part_kernel(const float* __restrict__ Xg,
                                                        float* __restrict__ tbl) {
    const int t = threadIdx.x, w = t >> 6, l = t & 63;
    const int rt = blockIdx.x >> 3, ks = blockIdx.x & 7;
    const int r = l & 15, kg = l >> 4;

    __shared__ float red[4][16][NFP + 1];

    const unsigned* WbU = (const unsigned*)(tbl + WB_OFF);
    f32x4 acc0 = {0.f, 0.f, 0.f, 0.f};
    f32x4 acc1 = acc0, acc2 = acc0;

    const float*    xrow = Xg + (size_t)(rt * 16 + r) * D + kg * 8;
    const unsigned* b0p = WbU + (size_t)(r)      * (D / 2) + kg * 4;
    const unsigned* b1p = WbU + (size_t)(16 + r) * (D / 2) + kg * 4;
    const unsigned* b2p = WbU + (size_t)(32 + r) * (D / 2) + kg * 4;
    const int kbase = ks * 2048 + w * 512;

    #pragma unroll 4
    for (int kk = 0; kk < 512; kk += 32) {
        const int kb = kbase + kk;
        float4 xa = *(const float4*)(xrow + kb);
        float4 xb = *(const float4*)(xrow + kb + 4);
        FragU af;
        af.u[0] = bpack(xa.x, xa.y); af.u[1] = bpack(xa.z, xa.w);
        af.u[2] = bpack(xb.x, xb.y); af.u[3] = bpack(xb.z, xb.w);
        const int ku = kb >> 1;
        bf16x8 b0 = *(const bf16x8*)(b0p + ku);
        bf16x8 b1 = *(const bf16x8*)(b1p + ku);
        bf16x8 b2 = *(const bf16x8*)(b2p + ku);
        acc0 = __builtin_amdgcn_mfma_f32_16x16x32_bf16(af.b, b0, acc0, 0, 0, 0);
        acc1 = __builtin_amdgcn_mfma_f32_16x16x32_bf16(af.b, b1, acc1, 0, 0, 0);
        acc2 = __builtin_amdgcn_mfma_f32_16x16x32_bf16(af.b, b2, acc2, 0, 0, 0);
    }

    #pragma unroll
    for (int q = 0; q < 4; ++q) {
        red[w][kg * 4 + q][r]      = acc0[q];
        red[w][kg * 4 + q][16 + r] = acc1[q];
        red[w][kg * 4 + q][32 + r] = acc2[q];
    }
    __syncthreads();

    float* c0p = tbl + C0P_OFF;
    for (int e = t; e < 16 * NF; e += 256) {
        const int row = e / NF, fl = e - row * NF;
        float s = red[0][row][fl] + red[1][row][fl] +
                  red[2][row][fl] + red[3][row][fl];
        c0p[((size_t)(rt * 16 + row) * KSPLIT + ks) * NF + fl] = s;
    }
}

// ---------------------------------------------------------------------------
// R: reduce K-split partials + 40-step recurrence -> aT[row][j] (coalesced).
// grid 256 (was 128 — half the chip idle), TPB 512, one wave per row.
// ---------------------------------------------------------------------------
__global__ __launch_bounds__(512) void reduce_rec_kernel(const float* __restrict__ Bg,
                                                         float* __restrict__ tbl) {
    const int t = threadIdx.x;
    const int wave = t >> 6, lane = t & 63;

    __shared__ float gts[NF][NF + 1];
    __shared__ float bsS[NF];
    for (int e = t; e < NF * NF; e += 512) {
        const int jj = e % NF;
        gts[e / NF][jj] = tbl[UW_OFF + e] + tbl[COEF_OFF + jj] * tbl[WW_OFF + e];
    }
    if (t < NF) bsS[t] = Bg[t];
    __syncthreads();

    const int g = blockIdx.x * 8 + wave;
    const float* cp = tbl + C0P_OFF + (size_t)g * (KSPLIT * NF);

    float c0 = 0.f;
    if (lane < NF) {
        #pragma unroll
        for (int s = 0; s < KSPLIT; ++s) c0 += cp[s * NF + lane];
        c0 += bsS[lane];
    }

    float aj = 0.f;
    for (int k = 0; k < NF; ++k) {
        float gv = (lane < k) ? gts[k][lane] : 0.f;
        float tv = aj * gv;
        #pragma unroll
        for (int off = 32; off >= 1; off >>= 1) tv += __shfl_xor(tv, off);
        float ck = __shfl(c0, k);
        float ak = tanhf(ck + tv);
        if (lane == k) aj = ak;
    }
    if (lane < NF) tbl[AT_OFF + (size_t)g * NF + lane] = aj;   // [S][NF] coalesced
}

// ---------------------------------------------------------------------------
// C: out[r] = x0[r] + sum_k a[r][k] * uhat_k.
// NEW: 16 rows/block (grid 128x8=1024) — halves UH L2 re-read traffic
// (672->336 MB). NT X loads (last use; keeps UH hot in L2) + NT out stores.
// launch_bounds(256,2): o[16] f4 = 64 VGPR alone; cap must be >=128.
// ---------------------------------------------------------------------------
__global__ __launch_bounds__(256, 2) void apply_kernel(const float* __restrict__ Xg,
                                                       const float* __restrict__ tbl,
                                                       float* __restrict__ Og) {
    const int bid = blockIdx.x;
    const int rblk = bid >> 3, cq = bid & 7;
    const int t = threadIdx.x;
    const int r0 = rblk * 16;

    __shared__ __align__(16) float aL[NF][16];
    for (int e = t; e < NF * 16; e += 256) {
        const int r = e / NF, k = e - r * NF;       // coalesced [S][NF] read
        aL[k][r] = tbl[AT_OFF + (size_t)(r0 + r) * NF + k];
    }
    __syncthreads();

    const f32x4* X4  = (const f32x4*)Xg;
    const f32x4* UH4 = (const f32x4*)(tbl + UH_OFF);
    f32x4* O4 = (f32x4*)Og;

    #pragma unroll 1
    for (int p = 0; p < 2; ++p) {
        const int col = cq * 512 + p * 256 + t;
        f32x4 o[16];
        #pragma unroll
        for (int r = 0; r < 16; ++r)
            o[r] = __builtin_nontemporal_load(&X4[(size_t)(r0 + r) * D4 + col]);

        #pragma unroll 4
        for (int k = 0; k < NF; ++k) {
            f32x4 uh = UH4[(size_t)k * D4 + col];
            const float4 a0 = *(const float4*)&aL[k][0];
            const float4 a1 = *(const float4*)&aL[k][4];
            const float4 a2 = *(const float4*)&aL[k][8];
            const float4 a3 = *(const float4*)&aL[k][12];
            o[0]  += uh * a0.x; o[1]  += uh * a0.y; o[2]  += uh * a0.z; o[3]  += uh * a0.w;
            o[4]  += uh * a1.x; o[5]  += uh * a1.y; o[6]  += uh * a1.z; o[7]  += uh * a1.w;
            o[8]  += uh * a2.x; o[9]  += uh * a2.y; o[10] += uh * a2.z; o[11] += uh * a2.w;
            o[12] += uh * a3.x; o[13] += uh * a3.y; o[14] += uh * a3.z; o[15] += uh * a3.w;
        }
        #pragma unroll
        for (int r = 0; r < 16; ++r)
            __builtin_nontemporal_store(o[r], &O4[(size_t)(r0 + r) * D4 + col]);
    }
}

// ---------------------------------------------------------------------------
// Fallback (ws too small): R5's proven scalar kernel.
// ---------------------------------------------------------------------------
__global__ __launch_bounds__(TPB) void flow_main_fb(const float* __restrict__ Xg,
                                                    const float* __restrict__ Wg,
                                                    const float* __restrict__ Ug,
                                                    const float* __restrict__ Bg,
                                                    const float* __restrict__ tbl,
                                                    float* __restrict__ Og) {
    const int t = threadIdx.x;
    const int wave = t >> 6, lane = t & 63;
    const int rowBase = blockIdx.x * ROWS;

    __shared__ __align__(16) float xs[2][ROWS][CHUNK];
    __shared__ __align__(16) float gts[NF][NF + 1];
    __shared__ __align__(16) float c0p[NF][ROWS];
    __shared__ __align__(16) float aTs[NF][ROWS];
    __shared__ float bsS[NF];
    __shared__ float coefS[NF];

    const float4* X4 = (const float4*)Xg;
    const float4* W4 = (const float4*)Wg;
    const float4* U4 = (const float4*)Ug;

    for (int e = t; e < NF * NF; e += TPB) {
        const int jj = e % NF;
        gts[e / NF][jj] = tbl[UW_OFF + e] + tbl[COEF_OFF + jj] * tbl[WW_OFF + e];
    }
    if (t < NF) { bsS[t] = Bg[t]; coefS[t] = tbl[COEF_OFF + t]; }

    const int srow = (t >> 8) * 2;
    const int sc4  = t & 255;

    float4 p0 = X4[(size_t)(rowBase + srow)     * D4 + sc4];
    float4 p1 = X4[(size_t)(rowBase + srow + 1) * D4 + sc4];
    *(float4*)&xs[0][srow][sc4 * 4]     = p0;
    *(float4*)&xs[0][srow + 1][sc4 * 4] = p1;
    __syncthreads();

    const int kt = wave & 7, rt = wave >> 3;
    const int k0 = kt * 5, r0 = rt * 4;

    float acc[4][5];
    #pragma unroll
    for (int r = 0; r < 4; ++r)
        #pragma unroll
        for (int kk = 0; kk < 5; ++kk) acc[r][kk] = 0.f;

    int b = 0;
    for (int c = 0; c < NCHUNK; ++c) {
        if (c + 1 < NCHUNK) {
            p0 = X4[(size_t)(rowBase + srow)     * D4 + (c + 1) * CH4 + sc4];
            p1 = X4[(size_t)(rowBase + srow + 1) * D4 + (c + 1) * CH4 + sc4];
        }
        #pragma unroll 1
        for (int s = 0; s < 4; ++s) {
            const int col4 = c * CH4 + s * 64 + lane;
            float4 wv[5];
            #pragma unroll
            for (int kk = 0; kk < 5; ++kk)
                wv[kk] = W4[(size_t)(k0 + kk) * D4 + col4];
            const int lc = (s * 64 + lane) * 4;
            #pragma unroll
            for (int r = 0; r < 4; ++r) {
                float4 xv = *(const float4*)&xs[b][r0 + r][lc];
                #pragma unroll
                for (int kk = 0; kk < 5; ++kk)
                    acc[r][kk] = fmaf(xv.x, wv[kk].x,
                                 fmaf(xv.y, wv[kk].y,
                                 fmaf(xv.z, wv[kk].z,
                                 fmaf(xv.w, wv[kk].w, acc[r][kk]))));
            }
        }
        if (c + 1 < NCHUNK) {
            *(float4*)&xs[b ^ 1][srow][sc4 * 4]     = p0;
            *(float4*)&xs[b ^ 1][srow + 1][sc4 * 4] = p1;
        }
        __syncthreads();
        b ^= 1;
    }

    #pragma unroll
    for (int r = 0; r < 4; ++r)
        #pragma unroll
        for (int kk = 0; kk < 5; ++kk) {
            float v = acc[r][kk];
            #pragma unroll
            for (int off = 32; off >= 1; off >>= 1) v += __shfl_xor(v, off);
            acc[r][kk] = v;
        }
    if (lane == 0) {
        #pragma unroll
        for (int kk = 0; kk < 5; ++kk)
            #pragma unroll
            for (int r = 0; r < 4; ++r)
                c0p[k0 + kk][r0 + r] = acc[r][kk];
    }
    __syncthreads();

    float4 o[ROWS];
    {
        const int col = wave * 64 + lane;
        #pragma unroll
        for (int r = 0; r < ROWS; ++r)
            o[r] = X4[(size_t)(rowBase + r) * D4 + col];
    }

    if (wave < ROWS) {
        const int r = wave, j = lane;
        float aj = 0.f;
        for (int k = 0; k < NF; ++k) {
            float gv = (j < k) ? gts[k][j] : 0.f;
            float tv = aj * gv;
            #pragma unroll
            for (int off = 32; off >= 1; off >>= 1) tv += __shfl_xor(tv, off);
            float sum = c0p[k][r] + bsS[k] + tv;
            float ak = tanhf(sum);
            if (j == k) aj = ak;
        }
        if (j < NF) aTs[j][r] = aj;
    }
    __syncthreads();

    float4* O4 = (float4*)Og;
    #pragma unroll 1
    for (int p = 0; p < 4; ++p) {
        const int col = p * 1024 + wave * 64 + lane;
        if (p > 0) {
            #pragma unroll
            for (int r = 0; r < ROWS; ++r)
                o[r] = X4[(size_t)(rowBase + r) * D4 + col];
        }
        #pragma unroll 2
        for (int k = 0; k < NF; ++k) {
            float4 uu = U4[(size_t)k * D4 + col];
            float4 wv = W4[(size_t)k * D4 + col];
            const float cf = coefS[k];
            float4 uh;
            uh.x = fmaf(cf, wv.x, uu.x);
            uh.y = fmaf(cf, wv.y, uu.y);
            uh.z = fmaf(cf, wv.z, uu.z);
            uh.w = fmaf(cf, wv.w, uu.w);
            float4 alo = *(const float4*)&aTs[k][0];
            float4 ahi = *(const float4*)&aTs[k][4];
            fma4(o[0], alo.x, uh); fma4(o[1], alo.y, uh);
            fma4(o[2], alo.z, uh); fma4(o[3], alo.w, uh);
            fma4(o[4], ahi.x, uh); fma4(o[5], ahi.y, uh);
            fma4(o[6], ahi.z, uh); fma4(o[7], ahi.w, uh);
        }
        #pragma unroll
        for (int r = 0; r < ROWS; ++r)
            O4[(size_t)(rowBase + r) * D4 + col] = o[r];
    }
}

extern "C" void kernel_launch(void* const* d_in, const int* in_sizes, int n_in,
                              void* d_out, int out_size, void* d_ws, size_t ws_size,
                              hipStream_t stream) {
    const float* X  = (const float*)d_in[0];
    const float* Wg = (const float*)d_in[1];
    const float* Ug = (const float*)d_in[2];
    const float* Bg = (const float*)d_in[3];
    float* out = (float*)d_out;
    float* tbl = (float*)d_ws;

    const bool fast = ws_size >= (size_t)WS_NEED * sizeof(float);

    if (fast) {
        pair_wb_kernel<<<NFP * 8, 512, 0, stream>>>(Wg, Ug, tbl, 1);
        gemm_part_kernel<<<(S / 16) * KSPLIT, 256, 0, stream>>>(X, tbl);
        reduce_rec_kernel<<<S / 8, 512, 0, stream>>>(Bg, tbl);
        apply_kernel<<<(S / 16) * 8, 256, 0, stream>>>(X, tbl, out);
    } else {
        pair_wb_kernel<<<NF * 8, 512, 0, stream>>>(Wg, Ug, tbl, 0);
        flow_main_fb<<<S / ROWS, TPB, 0, stream>>>(X, Wg, Ug, Bg, tbl, out);
    }
}

// Round 12
// 125.319 us; speedup vs baseline: 1.0596x; 1.0596x over previous
//
#include <hip/hip_runtime.h>
#include <math.h>

#define D      16384
#define D4     4096    // D/4
#define S      2048
#define NF     40
#define NFP    48      // padded flow count for MFMA (3 x 16)
#define ROWS   8
#define TPB    1024
#define CH4    256
#define CHUNK  1024
#define NCHUNK 16
#define KSPLIT 8       // K-splits in the MFMA GEMM

// ---- d_ws float offsets (fast path), ~7.2 MB total (ws measured 512 MB) ----
#define WW_OFF     0                        // WW[k][j] = w_j . w_k   (1600)
#define UW_OFF     1600                     // UW[k][j] = u_j . w_k   (1600)
#define COEF_OFF   3200                     // coef[j]                (40)
#define AT_OFF     4096                     // aT[S][NF] fp32         (81920)
#define WB_OFF     (AT_OFF + NF * S)        // Wb bf16 [NFP][D] as u32 (NFP*D/2 slots)
#define C0P_OFF    (WB_OFF + (NFP * D) / 2) // c0 partials [S][KSPLIT][NF]  (655360)
#define UH_OFF     (C0P_OFF + S * KSPLIT * NF) // uhat fp32 [NF][D] (dedicated region)
#define WS_NEED    (UH_OFF + NF * D)

typedef __attribute__((ext_vector_type(8))) __bf16 bf16x8;
typedef __attribute__((ext_vector_type(4))) float  f32x4;
union FragU { unsigned u[4]; bf16x8 b; };

__device__ __forceinline__ float dot4(float4 a, float4 b) {
    return fmaf(a.x, b.x, fmaf(a.y, b.y, fmaf(a.z, b.z, a.w * b.w)));
}
__device__ __forceinline__ void fma4(float4& o, float a, float4 u) {
    o.x = fmaf(a, u.x, o.x); o.y = fmaf(a, u.y, o.y);
    o.z = fmaf(a, u.z, o.z); o.w = fmaf(a, u.w, o.w);
}
// fp32 -> bf16 (RNE) pair pack: returns (lo | hi<<16)
__device__ __forceinline__ unsigned bpack(float lo, float hi) {
    unsigned a = __float_as_uint(lo);
    unsigned b = __float_as_uint(hi);
    a += 0x7fffu + ((a >> 16) & 1u);
    b += 0x7fffu + ((b >> 16) & 1u);
    return (a >> 16) | (b & 0xffff0000u);
}

// ---------------------------------------------------------------------------
// P1: block (k, h), grid NFP*8 (fast) / NF*8 (fallback), TPB 512.
//   k<40: WW[k][j], UW[k][j] for j in [5h,5h+5); coef (local reduction);
//         if doWb: Wb bf16 slice h AND UH slice h = u + coef*w (reuses the
//         i==h W/U loads; zero extra global traffic).
//   k>=40: zero-pad Wb row slice.
// ---------------------------------------------------------------------------
__global__ __launch_bounds__(512) void pair_wb_kernel(const float* __restrict__ Wg,
                                                      const float* __restrict__ Ug,
                                                      float* __restrict__ tbl,
                                                      int doWb) {
    const int k = blockIdx.x >> 3;
    const int h = blockIdx.x & 7;
    const int t = threadIdx.x;
    uint2* Wb2 = (uint2*)((unsigned*)(tbl + WB_OFF) + (size_t)k * (D / 2));

    if (k >= NF) {                       // zero-pad rows 40..47 (fast path only)
        Wb2[h * 512 + t] = make_uint2(0u, 0u);
        return;
    }

    const int j0 = h * 5;
    const int wave = t >> 6, lane = t & 63;
    const float4* W4 = (const float4*)Wg;
    const float4* U4 = (const float4*)Ug;

    float ww[5], wu[5], wkk = 0.f, wku = 0.f;
    float4 wkSave, ukSave;
    #pragma unroll
    for (int j = 0; j < 5; ++j) { ww[j] = 0.f; wu[j] = 0.f; }

    for (int i = 0; i < 8; ++i) {
        const int pos = i * 512 + t;
        float4 wk = W4[(size_t)k * D4 + pos];
        float4 uk = U4[(size_t)k * D4 + pos];
        if (i == h) { wkSave = wk; ukSave = uk; }
        wkk += dot4(wk, wk);
        wku += dot4(wk, uk);
        #pragma unroll
        for (int j = 0; j < 5; ++j) {
            float4 wj = W4[(size_t)(j0 + j) * D4 + pos];
            float4 uj = U4[(size_t)(j0 + j) * D4 + pos];
            ww[j] += dot4(wk, wj);
            wu[j] += dot4(wk, uj);
        }
    }

    if (doWb) {
        uint2 p;
        p.x = bpack(wkSave.x, wkSave.y);
        p.y = bpack(wkSave.z, wkSave.w);
        Wb2[h * 512 + t] = p;
    }

    float v[12];
    #pragma unroll
    for (int j = 0; j < 5; ++j) { v[j] = ww[j]; v[5 + j] = wu[j]; }
    v[10] = wkk; v[11] = wku;
    #pragma unroll
    for (int e = 0; e < 12; ++e) {
        #pragma unroll
        for (int off = 32; off >= 1; off >>= 1) v[e] += __shfl_xor(v[e], off);
    }

    __shared__ float red[8][12];
    __shared__ float fin[12];
    __shared__ float coefL;
    if (lane == 0) {
        #pragma unroll
        for (int e = 0; e < 12; ++e) red[wave][e] = v[e];
    }
    __syncthreads();
    if (t < 12) {
        float s = 0.f;
        #pragma unroll
        for (int w = 0; w < 8; ++w) s += red[w][t];
        fin[t] = s;
        if (t < 5)       tbl[WW_OFF + k * NF + j0 + t] = s;
        else if (t < 10) tbl[UW_OFF + k * NF + j0 + (t - 5)] = s;
    }
    __syncthreads();
    if (t == 0) {
        float wwd = fin[10], wud = fin[11];
        float sp = (wud > 0.f) ? (wud + log1pf(expf(-wud))) : log1pf(expf(wud));
        float cf = ((-1.f + sp) - wud) / wwd;
        coefL = cf;
        if (h == 0) tbl[COEF_OFF + k] = cf;
    }
    __syncthreads();

    if (doWb) {   // UH slice h, from the saved i==h values
        const float cf = coefL;
        float4 r;
        r.x = fmaf(cf, wkSave.x, ukSave.x);
        r.y = fmaf(cf, wkSave.y, ukSave.y);
        r.z = fmaf(cf, wkSave.z, ukSave.z);
        r.w = fmaf(cf, wkSave.w, ukSave.w);
        ((float4*)(tbl + UH_OFF))[(size_t)k * D4 + h * 512 + t] = r;
    }
}

// ---------------------------------------------------------------------------
// G: MFMA partial GEMM. grid = 128 row-tiles x KSPLIT=8 -> 1024 blocks,
// TPB 256 (4 waves). Unchanged (proven, ~HBM-bound on X).
// ---------------------------------------------------------------------------
__global__ __launch_bounds__(256) void gemm_part_kernel(const float* __restrict__ Xg,
                                                        float* __restrict__ tbl) {
    const int t = threadIdx.x, w = t >> 6, l = t & 63;
    const int rt = blockIdx.x >> 3, ks = blockIdx.x & 7;
    const int r = l & 15, kg = l >> 4;

    __shared__ float red[4][16][NFP + 1];

    const unsigned* WbU = (const unsigned*)(tbl + WB_OFF);
    f32x4 acc0 = {0.f, 0.f, 0.f, 0.f};
    f32x4 acc1 = acc0, acc2 = acc0;

    const float*    xrow = Xg + (size_t)(rt * 16 + r) * D + kg * 8;
    const unsigned* b0p = WbU + (size_t)(r)      * (D / 2) + kg * 4;
    const unsigned* b1p = WbU + (size_t)(16 + r) * (D / 2) + kg * 4;
    const unsigned* b2p = WbU + (size_t)(32 + r) * (D / 2) + kg * 4;
    const int kbase = ks * 2048 + w * 512;

    #pragma unroll 4
    for (int kk = 0; kk < 512; kk += 32) {
        const int kb = kbase + kk;
        float4 xa = *(const float4*)(xrow + kb);
        float4 xb = *(const float4*)(xrow + kb + 4);
        FragU af;
        af.u[0] = bpack(xa.x, xa.y); af.u[1] = bpack(xa.z, xa.w);
        af.u[2] = bpack(xb.x, xb.y); af.u[3] = bpack(xb.z, xb.w);
        const int ku = kb >> 1;
        bf16x8 b0 = *(const bf16x8*)(b0p + ku);
        bf16x8 b1 = *(const bf16x8*)(b1p + ku);
        bf16x8 b2 = *(const bf16x8*)(b2p + ku);
        acc0 = __builtin_amdgcn_mfma_f32_16x16x32_bf16(af.b, b0, acc0, 0, 0, 0);
        acc1 = __builtin_amdgcn_mfma_f32_16x16x32_bf16(af.b, b1, acc1, 0, 0, 0);
        acc2 = __builtin_amdgcn_mfma_f32_16x16x32_bf16(af.b, b2, acc2, 0, 0, 0);
    }

    #pragma unroll
    for (int q = 0; q < 4; ++q) {
        red[w][kg * 4 + q][r]      = acc0[q];
        red[w][kg * 4 + q][16 + r] = acc1[q];
        red[w][kg * 4 + q][32 + r] = acc2[q];
    }
    __syncthreads();

    float* c0p = tbl + C0P_OFF;
    for (int e = t; e < 16 * NF; e += 256) {
        const int row = e / NF, fl = e - row * NF;
        float s = red[0][row][fl] + red[1][row][fl] +
                  red[2][row][fl] + red[3][row][fl];
        c0p[((size_t)(rt * 16 + row) * KSPLIT + ks) * NF + fl] = s;
    }
}

// ---------------------------------------------------------------------------
// R: reduce K-split partials + 40-step recurrence -> aT[row][j] (coalesced).
// grid 256, TPB 512, one wave per row (kept from R11 — 2x R10's parallelism).
// ---------------------------------------------------------------------------
__global__ __launch_bounds__(512) void reduce_rec_kernel(const float* __restrict__ Bg,
                                                         float* __restrict__ tbl) {
    const int t = threadIdx.x;
    const int wave = t >> 6, lane = t & 63;

    __shared__ float gts[NF][NF + 1];
    __shared__ float bsS[NF];
    for (int e = t; e < NF * NF; e += 512) {
        const int jj = e % NF;
        gts[e / NF][jj] = tbl[UW_OFF + e] + tbl[COEF_OFF + jj] * tbl[WW_OFF + e];
    }
    if (t < NF) bsS[t] = Bg[t];
    __syncthreads();

    const int g = blockIdx.x * 8 + wave;
    const float* cp = tbl + C0P_OFF + (size_t)g * (KSPLIT * NF);

    float c0 = 0.f;
    if (lane < NF) {
        #pragma unroll
        for (int s = 0; s < KSPLIT; ++s) c0 += cp[s * NF + lane];
        c0 += bsS[lane];
    }

    float aj = 0.f;
    for (int k = 0; k < NF; ++k) {
        float gv = (lane < k) ? gts[k][lane] : 0.f;
        float tv = aj * gv;
        #pragma unroll
        for (int off = 32; off >= 1; off >>= 1) tv += __shfl_xor(tv, off);
        float ck = __shfl(c0, k);
        float ak = tanhf(ck + tv);
        if (lane == k) aj = ak;
    }
    if (lane < NF) tbl[AT_OFF + (size_t)g * NF + lane] = aj;   // [S][NF] coalesced
}

// ---------------------------------------------------------------------------
// C: out[r] = x0[r] + sum_k a[r][k] * uhat_k.  EXACT R10 version (125.7 us):
// grid 2048 (256 row-blocks x 8 col-eighths), TPB 256, plain launch_bounds,
// 8 rows/block, regular X loads (L3-hot from gemm), NT out stores only.
// R11's 16-row + launch_bounds(256,2) + NT-loads regressed (occupancy 2
// waves/SIMD; NT-load defeated the L3 X residency) — reverted.
// Note cq = bid&7 with round-robin block->XCD dispatch already gives each
// XCD a single column-eighth -> UH slice (328 KB) is L2-resident per XCD.
// ---------------------------------------------------------------------------
__global__ __launch_bounds__(256) void apply_kernel(const float* __restrict__ Xg,
                                                    const float* __restrict__ tbl,
                                                    float* __restrict__ Og) {
    const int bid = blockIdx.x;
    const int rblk = bid >> 3, cq = bid & 7;
    const int t = threadIdx.x;
    const int r0 = rblk * 8;

    __shared__ __align__(16) float aL[NF][8];
    for (int e = t; e < NF * 8; e += 256) {
        const int r = e / NF, k = e - r * NF;       // coalesced [S][NF] read
        aL[k][r] = tbl[AT_OFF + (size_t)(r0 + r) * NF + k];
    }
    __syncthreads();

    const float4* X4  = (const float4*)Xg;
    const float4* UH4 = (const float4*)(tbl + UH_OFF);
    f32x4* O4 = (f32x4*)Og;

    #pragma unroll 1
    for (int p = 0; p < 2; ++p) {
        const int col = cq * 512 + p * 256 + t;
        float4 o[8];
        #pragma unroll
        for (int r = 0; r < 8; ++r)
            o[r] = X4[(size_t)(r0 + r) * D4 + col];

        #pragma unroll 4
        for (int k = 0; k < NF; ++k) {
            float4 uh = UH4[(size_t)k * D4 + col];
            float4 alo = *(const float4*)&aL[k][0];
            float4 ahi = *(const float4*)&aL[k][4];
            fma4(o[0], alo.x, uh); fma4(o[1], alo.y, uh);
            fma4(o[2], alo.z, uh); fma4(o[3], alo.w, uh);
            fma4(o[4], ahi.x, uh); fma4(o[5], ahi.y, uh);
            fma4(o[6], ahi.z, uh); fma4(o[7], ahi.w, uh);
        }
        #pragma unroll
        for (int r = 0; r < 8; ++r)
            __builtin_nontemporal_store(*(const f32x4*)&o[r],
                                        &O4[(size_t)(r0 + r) * D4 + col]);
    }
}

// ---------------------------------------------------------------------------
// Fallback (ws too small): R5's proven scalar kernel.
// ---------------------------------------------------------------------------
__global__ __launch_bounds__(TPB) void flow_main_fb(const float* __restrict__ Xg,
                                                    const float* __restrict__ Wg,
                                                    const float* __restrict__ Ug,
                                                    const float* __restrict__ Bg,
                                                    const float* __restrict__ tbl,
                                                    float* __restrict__ Og) {
    const int t = threadIdx.x;
    const int wave = t >> 6, lane = t & 63;
    const int rowBase = blockIdx.x * ROWS;

    __shared__ __align__(16) float xs[2][ROWS][CHUNK];
    __shared__ __align__(16) float gts[NF][NF + 1];
    __shared__ __align__(16) float c0p[NF][ROWS];
    __shared__ __align__(16) float aTs[NF][ROWS];
    __shared__ float bsS[NF];
    __shared__ float coefS[NF];

    const float4* X4 = (const float4*)Xg;
    const float4* W4 = (const float4*)Wg;
    const float4* U4 = (const float4*)Ug;

    for (int e = t; e < NF * NF; e += TPB) {
        const int jj = e % NF;
        gts[e / NF][jj] = tbl[UW_OFF + e] + tbl[COEF_OFF + jj] * tbl[WW_OFF + e];
    }
    if (t < NF) { bsS[t] = Bg[t]; coefS[t] = tbl[COEF_OFF + t]; }

    const int srow = (t >> 8) * 2;
    const int sc4  = t & 255;

    float4 p0 = X4[(size_t)(rowBase + srow)     * D4 + sc4];
    float4 p1 = X4[(size_t)(rowBase + srow + 1) * D4 + sc4];
    *(float4*)&xs[0][srow][sc4 * 4]     = p0;
    *(float4*)&xs[0][srow + 1][sc4 * 4] = p1;
    __syncthreads();

    const int kt = wave & 7, rt = wave >> 3;
    const int k0 = kt * 5, r0 = rt * 4;

    float acc[4][5];
    #pragma unroll
    for (int r = 0; r < 4; ++r)
        #pragma unroll
        for (int kk = 0; kk < 5; ++kk) acc[r][kk] = 0.f;

    int b = 0;
    for (int c = 0; c < NCHUNK; ++c) {
        if (c + 1 < NCHUNK) {
            p0 = X4[(size_t)(rowBase + srow)     * D4 + (c + 1) * CH4 + sc4];
            p1 = X4[(size_t)(rowBase + srow + 1) * D4 + (c + 1) * CH4 + sc4];
        }
        #pragma unroll 1
        for (int s = 0; s < 4; ++s) {
            const int col4 = c * CH4 + s * 64 + lane;
            float4 wv[5];
            #pragma unroll
            for (int kk = 0; kk < 5; ++kk)
                wv[kk] = W4[(size_t)(k0 + kk) * D4 + col4];
            const int lc = (s * 64 + lane) * 4;
            #pragma unroll
            for (int r = 0; r < 4; ++r) {
                float4 xv = *(const float4*)&xs[b][r0 + r][lc];
                #pragma unroll
                for (int kk = 0; kk < 5; ++kk)
                    acc[r][kk] = fmaf(xv.x, wv[kk].x,
                                 fmaf(xv.y, wv[kk].y,
                                 fmaf(xv.z, wv[kk].z,
                                 fmaf(xv.w, wv[kk].w, acc[r][kk]))));
            }
        }
        if (c + 1 < NCHUNK) {
            *(float4*)&xs[b ^ 1][srow][sc4 * 4]     = p0;
            *(float4*)&xs[b ^ 1][srow + 1][sc4 * 4] = p1;
        }
        __syncthreads();
        b ^= 1;
    }

    #pragma unroll
    for (int r = 0; r < 4; ++r)
        #pragma unroll
        for (int kk = 0; kk < 5; ++kk) {
            float v = acc[r][kk];
            #pragma unroll
            for (int off = 32; off >= 1; off >>= 1) v += __shfl_xor(v, off);
            acc[r][kk] = v;
        }
    if (lane == 0) {
        #pragma unroll
        for (int kk = 0; kk < 5; ++kk)
            #pragma unroll
            for (int r = 0; r < 4; ++r)
                c0p[k0 + kk][r0 + r] = acc[r][kk];
    }
    __syncthreads();

    float4 o[ROWS];
    {
        const int col = wave * 64 + lane;
        #pragma unroll
        for (int r = 0; r < ROWS; ++r)
            o[r] = X4[(size_t)(rowBase + r) * D4 + col];
    }

    if (wave < ROWS) {
        const int r = wave, j = lane;
        float aj = 0.f;
        for (int k = 0; k < NF; ++k) {
            float gv = (j < k) ? gts[k][j] : 0.f;
            float tv = aj * gv;
            #pragma unroll
            for (int off = 32; off >= 1; off >>= 1) tv += __shfl_xor(tv, off);
            float sum = c0p[k][r] + bsS[k] + tv;
            float ak = tanhf(sum);
            if (j == k) aj = ak;
        }
        if (j < NF) aTs[j][r] = aj;
    }
    __syncthreads();

    float4* O4 = (float4*)Og;
    #pragma unroll 1
    for (int p = 0; p < 4; ++p) {
        const int col = p * 1024 + wave * 64 + lane;
        if (p > 0) {
            #pragma unroll
            for (int r = 0; r < ROWS; ++r)
                o[r] = X4[(size_t)(rowBase + r) * D4 + col];
        }
        #pragma unroll 2
        for (int k = 0; k < NF; ++k) {
            float4 uu = U4[(size_t)k * D4 + col];
            float4 wv = W4[(size_t)k * D4 + col];
            const float cf = coefS[k];
            float4 uh;
            uh.x = fmaf(cf, wv.x, uu.x);
            uh.y = fmaf(cf, wv.y, uu.y);
            uh.z = fmaf(cf, wv.z, uu.z);
            uh.w = fmaf(cf, wv.w, uu.w);
            float4 alo = *(const float4*)&aTs[k][0];
            float4 ahi = *(const float4*)&aTs[k][4];
            fma4(o[0], alo.x, uh); fma4(o[1], alo.y, uh);
            fma4(o[2], alo.z, uh); fma4(o[3], alo.w, uh);
            fma4(o[4], ahi.x, uh); fma4(o[5], ahi.y, uh);
            fma4(o[6], ahi.z, uh); fma4(o[7], ahi.w, uh);
        }
        #pragma unroll
        for (int r = 0; r < ROWS; ++r)
            O4[(size_t)(rowBase + r) * D4 + col] = o[r];
    }
}

extern "C" void kernel_launch(void* const* d_in, const int* in_sizes, int n_in,
                              void* d_out, int out_size, void* d_ws, size_t ws_size,
                              hipStream_t stream) {
    const float* X  = (const float*)d_in[0];
    const float* Wg = (const float*)d_in[1];
    const float* Ug = (const float*)d_in[2];
    const float* Bg = (const float*)d_in[3];
    float* out = (float*)d_out;
    float* tbl = (float*)d_ws;

    const bool fast = ws_size >= (size_t)WS_NEED * sizeof(float);

    if (fast) {
        pair_wb_kernel<<<NFP * 8, 512, 0, stream>>>(Wg, Ug, tbl, 1);
        gemm_part_kernel<<<(S / 16) * KSPLIT, 256, 0, stream>>>(X, tbl);
        reduce_rec_kernel<<<S / 8, 512, 0, stream>>>(Bg, tbl);
        apply_kernel<<<(S / 16) * 8 * 2, 256, 0, stream>>>(X, tbl, out);
    } else {
        pair_wb_kernel<<<NF * 8, 512, 0, stream>>>(Wg, Ug, tbl, 0);
        flow_main_fb<<<S / ROWS, TPB, 0, stream>>>(X, Wg, Ug, Bg, tbl, out);
    }
}

// Round 13
// 124.297 us; speedup vs baseline: 1.0683x; 1.0082x over previous
//
#include <hip/hip_runtime.h>
#include <math.h>

#define D      16384
#define D4     4096    // D/4
#define S      2048
#define NF     40
#define NFP    48      // padded flow count for MFMA (3 x 16)
#define ROWS   8
#define TPB    1024
#define CH4    256
#define CHUNK  1024
#define NCHUNK 16
#define KSPLIT 8       // K-splits in the MFMA GEMM

// ---- d_ws float offsets (fast path) ----
#define WW_OFF     0                        // WW[k][j] = w_j . w_k   (1600)
#define UW_OFF     1600                     // UW[k][j] = u_j . w_k   (1600)
#define COEF_OFF   3200                     // coef[j]                (40)
#define AT_OFF     4096                     // aT[S][NF] fp32         (81920)
#define WB_OFF     (AT_OFF + NF * S)        // Wb bf16 [NFP][D] as u32 (NFP*D/2 slots)
#define C0P_OFF    (WB_OFF + (NFP * D) / 2) // c0 partials [S][KSPLIT][NF]  (655360)
#define UHB_OFF    (C0P_OFF + S * KSPLIT * NF) // uhat bf16 [NF][D] as u32 (NF*D/2 slots)
#define WS_NEED    (UHB_OFF + (NF * D) / 2)

typedef __attribute__((ext_vector_type(8))) __bf16 bf16x8;
typedef __attribute__((ext_vector_type(4))) float  f32x4;
union FragU { unsigned u[4]; bf16x8 b; };

__device__ __forceinline__ float dot4(float4 a, float4 b) {
    return fmaf(a.x, b.x, fmaf(a.y, b.y, fmaf(a.z, b.z, a.w * b.w)));
}
__device__ __forceinline__ void fma4(float4& o, float a, float4 u) {
    o.x = fmaf(a, u.x, o.x); o.y = fmaf(a, u.y, o.y);
    o.z = fmaf(a, u.z, o.z); o.w = fmaf(a, u.w, o.w);
}
// fp32 -> bf16 (RNE) pair pack: returns (lo | hi<<16)
__device__ __forceinline__ unsigned bpack(float lo, float hi) {
    unsigned a = __float_as_uint(lo);
    unsigned b = __float_as_uint(hi);
    a += 0x7fffu + ((a >> 16) & 1u);
    b += 0x7fffu + ((b >> 16) & 1u);
    return (a >> 16) | (b & 0xffff0000u);
}

// ---------------------------------------------------------------------------
// P1: block (k, h), grid NFP*8 (fast) / NF*8 (fallback), TPB 512.
//   k<40: WW[k][j], UW[k][j] for j in [5h,5h+5); coef (local reduction);
//         if doWb: Wb bf16 slice h AND UHB bf16 slice h = bf16(u + coef*w)
//         (reuses the i==h W/U loads; zero extra global traffic).
//   k>=40: zero-pad Wb row slice.
// ---------------------------------------------------------------------------
__global__ __launch_bounds__(512) void pair_wb_kernel(const float* __restrict__ Wg,
                                                      const float* __restrict__ Ug,
                                                      float* __restrict__ tbl,
                                                      int doWb) {
    const int k = blockIdx.x >> 3;
    const int h = blockIdx.x & 7;
    const int t = threadIdx.x;
    uint2* Wb2 = (uint2*)((unsigned*)(tbl + WB_OFF) + (size_t)k * (D / 2));

    if (k >= NF) {                       // zero-pad rows 40..47 (fast path only)
        Wb2[h * 512 + t] = make_uint2(0u, 0u);
        return;
    }

    const int j0 = h * 5;
    const int wave = t >> 6, lane = t & 63;
    const float4* W4 = (const float4*)Wg;
    const float4* U4 = (const float4*)Ug;

    float ww[5], wu[5], wkk = 0.f, wku = 0.f;
    float4 wkSave, ukSave;
    #pragma unroll
    for (int j = 0; j < 5; ++j) { ww[j] = 0.f; wu[j] = 0.f; }

    for (int i = 0; i < 8; ++i) {
        const int pos = i * 512 + t;
        float4 wk = W4[(size_t)k * D4 + pos];
        float4 uk = U4[(size_t)k * D4 + pos];
        if (i == h) { wkSave = wk; ukSave = uk; }
        wkk += dot4(wk, wk);
        wku += dot4(wk, uk);
        #pragma unroll
        for (int j = 0; j < 5; ++j) {
            float4 wj = W4[(size_t)(j0 + j) * D4 + pos];
            float4 uj = U4[(size_t)(j0 + j) * D4 + pos];
            ww[j] += dot4(wk, wj);
            wu[j] += dot4(wk, uj);
        }
    }

    if (doWb) {
        uint2 p;
        p.x = bpack(wkSave.x, wkSave.y);
        p.y = bpack(wkSave.z, wkSave.w);
        Wb2[h * 512 + t] = p;
    }

    float v[12];
    #pragma unroll
    for (int j = 0; j < 5; ++j) { v[j] = ww[j]; v[5 + j] = wu[j]; }
    v[10] = wkk; v[11] = wku;
    #pragma unroll
    for (int e = 0; e < 12; ++e) {
        #pragma unroll
        for (int off = 32; off >= 1; off >>= 1) v[e] += __shfl_xor(v[e], off);
    }

    __shared__ float red[8][12];
    __shared__ float fin[12];
    __shared__ float coefL;
    if (lane == 0) {
        #pragma unroll
        for (int e = 0; e < 12; ++e) red[wave][e] = v[e];
    }
    __syncthreads();
    if (t < 12) {
        float s = 0.f;
        #pragma unroll
        for (int w = 0; w < 8; ++w) s += red[w][t];
        fin[t] = s;
        if (t < 5)       tbl[WW_OFF + k * NF + j0 + t] = s;
        else if (t < 10) tbl[UW_OFF + k * NF + j0 + (t - 5)] = s;
    }
    __syncthreads();
    if (t == 0) {
        float wwd = fin[10], wud = fin[11];
        float sp = (wud > 0.f) ? (wud + log1pf(expf(-wud))) : log1pf(expf(wud));
        float cf = ((-1.f + sp) - wud) / wwd;
        coefL = cf;
        if (h == 0) tbl[COEF_OFF + k] = cf;
    }
    __syncthreads();

    if (doWb) {   // UHB bf16 slice h, from the saved i==h values
        const float cf = coefL;
        float4 r;
        r.x = fmaf(cf, wkSave.x, ukSave.x);
        r.y = fmaf(cf, wkSave.y, ukSave.y);
        r.z = fmaf(cf, wkSave.z, ukSave.z);
        r.w = fmaf(cf, wkSave.w, ukSave.w);
        uint2 p;
        p.x = bpack(r.x, r.y);
        p.y = bpack(r.z, r.w);
        ((uint2*)((unsigned*)(tbl + UHB_OFF) + (size_t)k * (D / 2)))[h * 512 + t] = p;
    }
}

// ---------------------------------------------------------------------------
// G: MFMA partial GEMM. grid = 128 row-tiles x KSPLIT=8 -> 1024 blocks,
// TPB 256 (4 waves). Unchanged (proven).
// ---------------------------------------------------------------------------
__global__ __launch_bounds__(256) void gemm_part_kernel(const float* __restrict__ Xg,
                                                        float* __restrict__ tbl) {
    const int t = threadIdx.x, w = t >> 6, l = t & 63;
    const int rt = blockIdx.x >> 3, ks = blockIdx.x & 7;
    const int r = l & 15, kg = l >> 4;

    __shared__ float red[4][16][NFP + 1];

    const unsigned* WbU = (const unsigned*)(tbl + WB_OFF);
    f32x4 acc0 = {0.f, 0.f, 0.f, 0.f};
    f32x4 acc1 = acc0, acc2 = acc0;

    const float*    xrow = Xg + (size_t)(rt * 16 + r) * D + kg * 8;
    const unsigned* b0p = WbU + (size_t)(r)      * (D / 2) + kg * 4;
    const unsigned* b1p = WbU + (size_t)(16 + r) * (D / 2) + kg * 4;
    const unsigned* b2p = WbU + (size_t)(32 + r) * (D / 2) + kg * 4;
    const int kbase = ks * 2048 + w * 512;

    #pragma unroll 4
    for (int kk = 0; kk < 512; kk += 32) {
        const int kb = kbase + kk;
        float4 xa = *(const float4*)(xrow + kb);
        float4 xb = *(const float4*)(xrow + kb + 4);
        FragU af;
        af.u[0] = bpack(xa.x, xa.y); af.u[1] = bpack(xa.z, xa.w);
        af.u[2] = bpack(xb.x, xb.y); af.u[3] = bpack(xb.z, xb.w);
        const int ku = kb >> 1;
        bf16x8 b0 = *(const bf16x8*)(b0p + ku);
        bf16x8 b1 = *(const bf16x8*)(b1p + ku);
        bf16x8 b2 = *(const bf16x8*)(b2p + ku);
        acc0 = __builtin_amdgcn_mfma_f32_16x16x32_bf16(af.b, b0, acc0, 0, 0, 0);
        acc1 = __builtin_amdgcn_mfma_f32_16x16x32_bf16(af.b, b1, acc1, 0, 0, 0);
        acc2 = __builtin_amdgcn_mfma_f32_16x16x32_bf16(af.b, b2, acc2, 0, 0, 0);
    }

    #pragma unroll
    for (int q = 0; q < 4; ++q) {
        red[w][kg * 4 + q][r]      = acc0[q];
        red[w][kg * 4 + q][16 + r] = acc1[q];
        red[w][kg * 4 + q][32 + r] = acc2[q];
    }
    __syncthreads();

    float* c0p = tbl + C0P_OFF;
    for (int e = t; e < 16 * NF; e += 256) {
        const int row = e / NF, fl = e - row * NF;
        float s = red[0][row][fl] + red[1][row][fl] +
                  red[2][row][fl] + red[3][row][fl];
        c0p[((size_t)(rt * 16 + row) * KSPLIT + ks) * NF + fl] = s;
    }
}

// ---------------------------------------------------------------------------
// R: reduce K-split partials + 40-step recurrence -> aT[row][j] (coalesced).
// grid 256, TPB 512, one wave per row. Unchanged from R12.
// ---------------------------------------------------------------------------
__global__ __launch_bounds__(512) void reduce_rec_kernel(const float* __restrict__ Bg,
                                                         float* __restrict__ tbl) {
    const int t = threadIdx.x;
    const int wave = t >> 6, lane = t & 63;

    __shared__ float gts[NF][NF + 1];
    __shared__ float bsS[NF];
    for (int e = t; e < NF * NF; e += 512) {
        const int jj = e % NF;
        gts[e / NF][jj] = tbl[UW_OFF + e] + tbl[COEF_OFF + jj] * tbl[WW_OFF + e];
    }
    if (t < NF) bsS[t] = Bg[t];
    __syncthreads();

    const int g = blockIdx.x * 8 + wave;
    const float* cp = tbl + C0P_OFF + (size_t)g * (KSPLIT * NF);

    float c0 = 0.f;
    if (lane < NF) {
        #pragma unroll
        for (int s = 0; s < KSPLIT; ++s) c0 += cp[s * NF + lane];
        c0 += bsS[lane];
    }

    float aj = 0.f;
    for (int k = 0; k < NF; ++k) {
        float gv = (lane < k) ? gts[k][lane] : 0.f;
        float tv = aj * gv;
        #pragma unroll
        for (int off = 32; off >= 1; off >>= 1) tv += __shfl_xor(tv, off);
        float ck = __shfl(c0, k);
        float ak = tanhf(ck + tv);
        if (lane == k) aj = ak;
    }
    if (lane < NF) tbl[AT_OFF + (size_t)g * NF + lane] = aj;   // [S][NF] coalesced
}

// ---------------------------------------------------------------------------
// C: out[r] = x0[r] + sum_k a[r][k] * uhat_k.  R12 structure (proven 125 us)
// with ONE change: Û read as bf16 uint2 (8 B/k, halves L2 traffic 672->336 MB
// and the bytes on the 40-deep load chain). bf16->fp32 unpack is 2 bit-ops
// per element (exact). NT out stores kept.
// ---------------------------------------------------------------------------
__global__ __launch_bounds__(256) void apply_kernel(const float* __restrict__ Xg,
                                                    const float* __restrict__ tbl,
                                                    float* __restrict__ Og) {
    const int bid = blockIdx.x;
    const int rblk = bid >> 3, cq = bid & 7;
    const int t = threadIdx.x;
    const int r0 = rblk * 8;

    __shared__ __align__(16) float aL[NF][8];
    for (int e = t; e < NF * 8; e += 256) {
        const int r = e / NF, k = e - r * NF;       // coalesced [S][NF] read
        aL[k][r] = tbl[AT_OFF + (size_t)(r0 + r) * NF + k];
    }
    __syncthreads();

    const float4* X4 = (const float4*)Xg;
    const uint2* UHB2 = (const uint2*)((const unsigned*)(tbl + UHB_OFF));
    f32x4* O4 = (f32x4*)Og;

    #pragma unroll 1
    for (int p = 0; p < 2; ++p) {
        const int col = cq * 512 + p * 256 + t;
        float4 o[8];
        #pragma unroll
        for (int r = 0; r < 8; ++r)
            o[r] = X4[(size_t)(r0 + r) * D4 + col];

        #pragma unroll 4
        for (int k = 0; k < NF; ++k) {
            uint2 ub = UHB2[(size_t)k * D4 + col];   // D/4 uint2 per row
            float4 uh;
            uh.x = __uint_as_float(ub.x << 16);
            uh.y = __uint_as_float(ub.x & 0xffff0000u);
            uh.z = __uint_as_float(ub.y << 16);
            uh.w = __uint_as_float(ub.y & 0xffff0000u);
            float4 alo = *(const float4*)&aL[k][0];
            float4 ahi = *(const float4*)&aL[k][4];
            fma4(o[0], alo.x, uh); fma4(o[1], alo.y, uh);
            fma4(o[2], alo.z, uh); fma4(o[3], alo.w, uh);
            fma4(o[4], ahi.x, uh); fma4(o[5], ahi.y, uh);
            fma4(o[6], ahi.z, uh); fma4(o[7], ahi.w, uh);
        }
        #pragma unroll
        for (int r = 0; r < 8; ++r)
            __builtin_nontemporal_store(*(const f32x4*)&o[r],
                                        &O4[(size_t)(r0 + r) * D4 + col]);
    }
}

// ---------------------------------------------------------------------------
// Fallback (ws too small): R5's proven scalar kernel (does not use UHB).
// ---------------------------------------------------------------------------
__global__ __launch_bounds__(TPB) void flow_main_fb(const float* __restrict__ Xg,
                                                    const float* __restrict__ Wg,
                                                    const float* __restrict__ Ug,
                                                    const float* __restrict__ Bg,
                                                    const float* __restrict__ tbl,
                                                    float* __restrict__ Og) {
    const int t = threadIdx.x;
    const int wave = t >> 6, lane = t & 63;
    const int rowBase = blockIdx.x * ROWS;

    __shared__ __align__(16) float xs[2][ROWS][CHUNK];
    __shared__ __align__(16) float gts[NF][NF + 1];
    __shared__ __align__(16) float c0p[NF][ROWS];
    __shared__ __align__(16) float aTs[NF][ROWS];
    __shared__ float bsS[NF];
    __shared__ float coefS[NF];

    const float4* X4 = (const float4*)Xg;
    const float4* W4 = (const float4*)Wg;
    const float4* U4 = (const float4*)Ug;

    for (int e = t; e < NF * NF; e += TPB) {
        const int jj = e % NF;
        gts[e / NF][jj] = tbl[UW_OFF + e] + tbl[COEF_OFF + jj] * tbl[WW_OFF + e];
    }
    if (t < NF) { bsS[t] = Bg[t]; coefS[t] = tbl[COEF_OFF + t]; }

    const int srow = (t >> 8) * 2;
    const int sc4  = t & 255;

    float4 p0 = X4[(size_t)(rowBase + srow)     * D4 + sc4];
    float4 p1 = X4[(size_t)(rowBase + srow + 1) * D4 + sc4];
    *(float4*)&xs[0][srow][sc4 * 4]     = p0;
    *(float4*)&xs[0][srow + 1][sc4 * 4] = p1;
    __syncthreads();

    const int kt = wave & 7, rt = wave >> 3;
    const int k0 = kt * 5, r0 = rt * 4;

    float acc[4][5];
    #pragma unroll
    for (int r = 0; r < 4; ++r)
        #pragma unroll
        for (int kk = 0; kk < 5; ++kk) acc[r][kk] = 0.f;

    int b = 0;
    for (int c = 0; c < NCHUNK; ++c) {
        if (c + 1 < NCHUNK) {
            p0 = X4[(size_t)(rowBase + srow)     * D4 + (c + 1) * CH4 + sc4];
            p1 = X4[(size_t)(rowBase + srow + 1) * D4 + (c + 1) * CH4 + sc4];
        }
        #pragma unroll 1
        for (int s = 0; s < 4; ++s) {
            const int col4 = c * CH4 + s * 64 + lane;
            float4 wv[5];
            #pragma unroll
            for (int kk = 0; kk < 5; ++kk)
                wv[kk] = W4[(size_t)(k0 + kk) * D4 + col4];
            const int lc = (s * 64 + lane) * 4;
            #pragma unroll
            for (int r = 0; r < 4; ++r) {
                float4 xv = *(const float4*)&xs[b][r0 + r][lc];
                #pragma unroll
                for (int kk = 0; kk < 5; ++kk)
                    acc[r][kk] = fmaf(xv.x, wv[kk].x,
                                 fmaf(xv.y, wv[kk].y,
                                 fmaf(xv.z, wv[kk].z,
                                 fmaf(xv.w, wv[kk].w, acc[r][kk]))));
            }
        }
        if (c + 1 < NCHUNK) {
            *(float4*)&xs[b ^ 1][srow][sc4 * 4]     = p0;
            *(float4*)&xs[b ^ 1][srow + 1][sc4 * 4] = p1;
        }
        __syncthreads();
        b ^= 1;
    }

    #pragma unroll
    for (int r = 0; r < 4; ++r)
        #pragma unroll
        for (int kk = 0; kk < 5; ++kk) {
            float v = acc[r][kk];
            #pragma unroll
            for (int off = 32; off >= 1; off >>= 1) v += __shfl_xor(v, off);
            acc[r][kk] = v;
        }
    if (lane == 0) {
        #pragma unroll
        for (int kk = 0; kk < 5; ++kk)
            #pragma unroll
            for (int r = 0; r < 4; ++r)
                c0p[k0 + kk][r0 + r] = acc[r][kk];
    }
    __syncthreads();

    float4 o[ROWS];
    {
        const int col = wave * 64 + lane;
        #pragma unroll
        for (int r = 0; r < ROWS; ++r)
            o[r] = X4[(size_t)(rowBase + r) * D4 + col];
    }

    if (wave < ROWS) {
        const int r = wave, j = lane;
        float aj = 0.f;
        for (int k = 0; k < NF; ++k) {
            float gv = (j < k) ? gts[k][j] : 0.f;
            float tv = aj * gv;
            #pragma unroll
            for (int off = 32; off >= 1; off >>= 1) tv += __shfl_xor(tv, off);
            float sum = c0p[k][r] + bsS[k] + tv;
            float ak = tanhf(sum);
            if (j == k) aj = ak;
        }
        if (j < NF) aTs[j][r] = aj;
    }
    __syncthreads();

    float4* O4 = (float4*)Og;
    #pragma unroll 1
    for (int p = 0; p < 4; ++p) {
        const int col = p * 1024 + wave * 64 + lane;
        if (p > 0) {
            #pragma unroll
            for (int r = 0; r < ROWS; ++r)
                o[r] = X4[(size_t)(rowBase + r) * D4 + col];
        }
        #pragma unroll 2
        for (int k = 0; k < NF; ++k) {
            float4 uu = U4[(size_t)k * D4 + col];
            float4 wv = W4[(size_t)k * D4 + col];
            const float cf = coefS[k];
            float4 uh;
            uh.x = fmaf(cf, wv.x, uu.x);
            uh.y = fmaf(cf, wv.y, uu.y);
            uh.z = fmaf(cf, wv.z, uu.z);
            uh.w = fmaf(cf, wv.w, uu.w);
            float4 alo = *(const float4*)&aTs[k][0];
            float4 ahi = *(const float4*)&aTs[k][4];
            fma4(o[0], alo.x, uh); fma4(o[1], alo.y, uh);
            fma4(o[2], alo.z, uh); fma4(o[3], alo.w, uh);
            fma4(o[4], ahi.x, uh); fma4(o[5], ahi.y, uh);
            fma4(o[6], ahi.z, uh); fma4(o[7], ahi.w, uh);
        }
        #pragma unroll
        for (int r = 0; r < ROWS; ++r)
            O4[(size_t)(rowBase + r) * D4 + col] = o[r];
    }
}

extern "C" void kernel_launch(void* const* d_in, const int* in_sizes, int n_in,
                              void* d_out, int out_size, void* d_ws, size_t ws_size,
                              hipStream_t stream) {
    const float* X  = (const float*)d_in[0];
    const float* Wg = (const float*)d_in[1];
    const float* Ug = (const float*)d_in[2];
    const float* Bg = (const float*)d_in[3];
    float* out = (float*)d_out;
    float* tbl = (float*)d_ws;

    const bool fast = ws_size >= (size_t)WS_NEED * sizeof(float);

    if (fast) {
        pair_wb_kernel<<<NFP * 8, 512, 0, stream>>>(Wg, Ug, tbl, 1);
        gemm_part_kernel<<<(S / 16) * KSPLIT, 256, 0, stream>>>(X, tbl);
        reduce_rec_kernel<<<S / 8, 512, 0, stream>>>(Bg, tbl);
        apply_kernel<<<(S / 16) * 8 * 2, 256, 0, stream>>>(X, tbl, out);
    } else {
        pair_wb_kernel<<<NF * 8, 512, 0, stream>>>(Wg, Ug, tbl, 0);
        flow_main_fb<<<S / ROWS, TPB, 0, stream>>>(X, Wg, Ug, Bg, tbl, out);
    }
}

// Round 14
// 123.680 us; speedup vs baseline: 1.0736x; 1.0050x over previous
//
#include <hip/hip_runtime.h>
#include <math.h>

#define D      16384
#define D4     4096    // D/4
#define S      2048
#define NF     40
#define NFP    48      // padded flow count for MFMA (3 x 16)
#define ROWS   8
#define TPB    1024
#define CH4    256
#define CHUNK  1024
#define NCHUNK 16
#define KSPLIT 16      // K-splits in the MFMA GEMM (8->16: 8 waves/SIMD TLP)

// ---- d_ws float offsets (fast path) ----
#define WW_OFF     0                        // WW[k][j] = w_j . w_k   (1600)
#define UW_OFF     1600                     // UW[k][j] = u_j . w_k   (1600)
#define COEF_OFF   3200                     // coef[j]                (40)
#define AT_OFF     4096                     // aT[S][NF] fp32         (81920)
#define WB_OFF     (AT_OFF + NF * S)        // Wb bf16 [NFP][D] as u32 (NFP*D/2 slots)
#define C0P_OFF    (WB_OFF + (NFP * D) / 2) // c0 partials [S][KSPLIT][NF]
#define UHB_OFF    (C0P_OFF + S * KSPLIT * NF) // uhat bf16 [NF][D] as u32
#define WS_NEED    (UHB_OFF + (NF * D) / 2)

typedef __attribute__((ext_vector_type(8))) __bf16 bf16x8;
typedef __attribute__((ext_vector_type(4))) float  f32x4;
union FragU { unsigned u[4]; bf16x8 b; };

__device__ __forceinline__ float dot4(float4 a, float4 b) {
    return fmaf(a.x, b.x, fmaf(a.y, b.y, fmaf(a.z, b.z, a.w * b.w)));
}
__device__ __forceinline__ void fma4(float4& o, float a, float4 u) {
    o.x = fmaf(a, u.x, o.x); o.y = fmaf(a, u.y, o.y);
    o.z = fmaf(a, u.z, o.z); o.w = fmaf(a, u.w, o.w);
}
// fp32 -> bf16 (RNE) pair pack: returns (lo | hi<<16)
__device__ __forceinline__ unsigned bpack(float lo, float hi) {
    unsigned a = __float_as_uint(lo);
    unsigned b = __float_as_uint(hi);
    a += 0x7fffu + ((a >> 16) & 1u);
    b += 0x7fffu + ((b >> 16) & 1u);
    return (a >> 16) | (b & 0xffff0000u);
}

// ---------------------------------------------------------------------------
// P1: block (k, h), grid NFP*8 (fast) / NF*8 (fallback), TPB 512.
//   k<40: WW[k][j], UW[k][j] for j in [5h,5h+5); coef (local reduction);
//         if doWb: Wb bf16 slice h AND UHB bf16 slice h = bf16(u + coef*w).
//   k>=40: zero-pad Wb row slice.
// ---------------------------------------------------------------------------
__global__ __launch_bounds__(512) void pair_wb_kernel(const float* __restrict__ Wg,
                                                      const float* __restrict__ Ug,
                                                      float* __restrict__ tbl,
                                                      int doWb) {
    const int k = blockIdx.x >> 3;
    const int h = blockIdx.x & 7;
    const int t = threadIdx.x;
    uint2* Wb2 = (uint2*)((unsigned*)(tbl + WB_OFF) + (size_t)k * (D / 2));

    if (k >= NF) {                       // zero-pad rows 40..47 (fast path only)
        Wb2[h * 512 + t] = make_uint2(0u, 0u);
        return;
    }

    const int j0 = h * 5;
    const int wave = t >> 6, lane = t & 63;
    const float4* W4 = (const float4*)Wg;
    const float4* U4 = (const float4*)Ug;

    float ww[5], wu[5], wkk = 0.f, wku = 0.f;
    float4 wkSave, ukSave;
    #pragma unroll
    for (int j = 0; j < 5; ++j) { ww[j] = 0.f; wu[j] = 0.f; }

    for (int i = 0; i < 8; ++i) {
        const int pos = i * 512 + t;
        float4 wk = W4[(size_t)k * D4 + pos];
        float4 uk = U4[(size_t)k * D4 + pos];
        if (i == h) { wkSave = wk; ukSave = uk; }
        wkk += dot4(wk, wk);
        wku += dot4(wk, uk);
        #pragma unroll
        for (int j = 0; j < 5; ++j) {
            float4 wj = W4[(size_t)(j0 + j) * D4 + pos];
            float4 uj = U4[(size_t)(j0 + j) * D4 + pos];
            ww[j] += dot4(wk, wj);
            wu[j] += dot4(wk, uj);
        }
    }

    if (doWb) {
        uint2 p;
        p.x = bpack(wkSave.x, wkSave.y);
        p.y = bpack(wkSave.z, wkSave.w);
        Wb2[h * 512 + t] = p;
    }

    float v[12];
    #pragma unroll
    for (int j = 0; j < 5; ++j) { v[j] = ww[j]; v[5 + j] = wu[j]; }
    v[10] = wkk; v[11] = wku;
    #pragma unroll
    for (int e = 0; e < 12; ++e) {
        #pragma unroll
        for (int off = 32; off >= 1; off >>= 1) v[e] += __shfl_xor(v[e], off);
    }

    __shared__ float red[8][12];
    __shared__ float fin[12];
    __shared__ float coefL;
    if (lane == 0) {
        #pragma unroll
        for (int e = 0; e < 12; ++e) red[wave][e] = v[e];
    }
    __syncthreads();
    if (t < 12) {
        float s = 0.f;
        #pragma unroll
        for (int w = 0; w < 8; ++w) s += red[w][t];
        fin[t] = s;
        if (t < 5)       tbl[WW_OFF + k * NF + j0 + t] = s;
        else if (t < 10) tbl[UW_OFF + k * NF + j0 + (t - 5)] = s;
    }
    __syncthreads();
    if (t == 0) {
        float wwd = fin[10], wud = fin[11];
        float sp = (wud > 0.f) ? (wud + log1pf(expf(-wud))) : log1pf(expf(wud));
        float cf = ((-1.f + sp) - wud) / wwd;
        coefL = cf;
        if (h == 0) tbl[COEF_OFF + k] = cf;
    }
    __syncthreads();

    if (doWb) {   // UHB bf16 slice h, from the saved i==h values
        const float cf = coefL;
        float4 r;
        r.x = fmaf(cf, wkSave.x, ukSave.x);
        r.y = fmaf(cf, wkSave.y, ukSave.y);
        r.z = fmaf(cf, wkSave.z, ukSave.z);
        r.w = fmaf(cf, wkSave.w, ukSave.w);
        uint2 p;
        p.x = bpack(r.x, r.y);
        p.y = bpack(r.z, r.w);
        ((uint2*)((unsigned*)(tbl + UHB_OFF) + (size_t)k * (D / 2)))[h * 512 + t] = p;
    }
}

// ---------------------------------------------------------------------------
// G: MFMA partial GEMM. grid = 128 row-tiles x KSPLIT=16 -> 2048 blocks,
// TPB 256 (4 waves) -> 8 blocks/CU = 8 waves/SIMD (was 4 — TLP for the
// 16-row-scattered 128B X load pattern). Per wave: 256-col slice, 8 iters.
// ---------------------------------------------------------------------------
__global__ __launch_bounds__(256) void gemm_part_kernel(const float* __restrict__ Xg,
                                                        float* __restrict__ tbl) {
    const int t = threadIdx.x, w = t >> 6, l = t & 63;
    const int rt = blockIdx.x >> 4, ks = blockIdx.x & 15;
    const int r = l & 15, kg = l >> 4;

    __shared__ float red[4][16][NFP + 1];

    const unsigned* WbU = (const unsigned*)(tbl + WB_OFF);
    f32x4 acc0 = {0.f, 0.f, 0.f, 0.f};
    f32x4 acc1 = acc0, acc2 = acc0;

    const float*    xrow = Xg + (size_t)(rt * 16 + r) * D + kg * 8;
    const unsigned* b0p = WbU + (size_t)(r)      * (D / 2) + kg * 4;
    const unsigned* b1p = WbU + (size_t)(16 + r) * (D / 2) + kg * 4;
    const unsigned* b2p = WbU + (size_t)(32 + r) * (D / 2) + kg * 4;
    const int kbase = ks * (D / KSPLIT) + w * (D / KSPLIT / 4);

    #pragma unroll 4
    for (int kk = 0; kk < D / KSPLIT / 4; kk += 32) {
        const int kb = kbase + kk;
        float4 xa = *(const float4*)(xrow + kb);
        float4 xb = *(const float4*)(xrow + kb + 4);
        FragU af;
        af.u[0] = bpack(xa.x, xa.y); af.u[1] = bpack(xa.z, xa.w);
        af.u[2] = bpack(xb.x, xb.y); af.u[3] = bpack(xb.z, xb.w);
        const int ku = kb >> 1;
        bf16x8 b0 = *(const bf16x8*)(b0p + ku);
        bf16x8 b1 = *(const bf16x8*)(b1p + ku);
        bf16x8 b2 = *(const bf16x8*)(b2p + ku);
        acc0 = __builtin_amdgcn_mfma_f32_16x16x32_bf16(af.b, b0, acc0, 0, 0, 0);
        acc1 = __builtin_amdgcn_mfma_f32_16x16x32_bf16(af.b, b1, acc1, 0, 0, 0);
        acc2 = __builtin_amdgcn_mfma_f32_16x16x32_bf16(af.b, b2, acc2, 0, 0, 0);
    }

    #pragma unroll
    for (int q = 0; q < 4; ++q) {
        red[w][kg * 4 + q][r]      = acc0[q];
        red[w][kg * 4 + q][16 + r] = acc1[q];
        red[w][kg * 4 + q][32 + r] = acc2[q];
    }
    __syncthreads();

    float* c0p = tbl + C0P_OFF;
    for (int e = t; e < 16 * NF; e += 256) {
        const int row = e / NF, fl = e - row * NF;
        float s = red[0][row][fl] + red[1][row][fl] +
                  red[2][row][fl] + red[3][row][fl];
        c0p[((size_t)(rt * 16 + row) * KSPLIT + ks) * NF + fl] = s;
    }
}

// ---------------------------------------------------------------------------
// R: reduce K-split partials + 40-step recurrence -> aT[row][j] (coalesced).
// grid 256, TPB 512, one wave per row. Now sums 16 partials.
// ---------------------------------------------------------------------------
__global__ __launch_bounds__(512) void reduce_rec_kernel(const float* __restrict__ Bg,
                                                         float* __restrict__ tbl) {
    const int t = threadIdx.x;
    const int wave = t >> 6, lane = t & 63;

    __shared__ float gts[NF][NF + 1];
    __shared__ float bsS[NF];
    for (int e = t; e < NF * NF; e += 512) {
        const int jj = e % NF;
        gts[e / NF][jj] = tbl[UW_OFF + e] + tbl[COEF_OFF + jj] * tbl[WW_OFF + e];
    }
    if (t < NF) bsS[t] = Bg[t];
    __syncthreads();

    const int g = blockIdx.x * 8 + wave;
    const float* cp = tbl + C0P_OFF + (size_t)g * (KSPLIT * NF);

    float c0 = 0.f;
    if (lane < NF) {
        #pragma unroll
        for (int s = 0; s < KSPLIT; ++s) c0 += cp[s * NF + lane];
        c0 += bsS[lane];
    }

    float aj = 0.f;
    for (int k = 0; k < NF; ++k) {
        float gv = (lane < k) ? gts[k][lane] : 0.f;
        float tv = aj * gv;
        #pragma unroll
        for (int off = 32; off >= 1; off >>= 1) tv += __shfl_xor(tv, off);
        float ck = __shfl(c0, k);
        float ak = tanhf(ck + tv);
        if (lane == k) aj = ak;
    }
    if (lane < NF) tbl[AT_OFF + (size_t)g * NF + lane] = aj;   // [S][NF] coalesced
}

// ---------------------------------------------------------------------------
// C: out[r] = x0[r] + sum_k a[r][k] * uhat_k.  Unchanged from R13 (proven):
// grid 2048, TPB 256, 8 rows/block, bf16 Û uint2 loads, NT out stores.
// ---------------------------------------------------------------------------
__global__ __launch_bounds__(256) void apply_kernel(const float* __restrict__ Xg,
                                                    const float* __restrict__ tbl,
                                                    float* __restrict__ Og) {
    const int bid = blockIdx.x;
    const int rblk = bid >> 3, cq = bid & 7;
    const int t = threadIdx.x;
    const int r0 = rblk * 8;

    __shared__ __align__(16) float aL[NF][8];
    for (int e = t; e < NF * 8; e += 256) {
        const int r = e / NF, k = e - r * NF;       // coalesced [S][NF] read
        aL[k][r] = tbl[AT_OFF + (size_t)(r0 + r) * NF + k];
    }
    __syncthreads();

    const float4* X4 = (const float4*)Xg;
    const uint2* UHB2 = (const uint2*)((const unsigned*)(tbl + UHB_OFF));
    f32x4* O4 = (f32x4*)Og;

    #pragma unroll 1
    for (int p = 0; p < 2; ++p) {
        const int col = cq * 512 + p * 256 + t;
        float4 o[8];
        #pragma unroll
        for (int r = 0; r < 8; ++r)
            o[r] = X4[(size_t)(r0 + r) * D4 + col];

        #pragma unroll 4
        for (int k = 0; k < NF; ++k) {
            uint2 ub = UHB2[(size_t)k * D4 + col];
            float4 uh;
            uh.x = __uint_as_float(ub.x << 16);
            uh.y = __uint_as_float(ub.x & 0xffff0000u);
            uh.z = __uint_as_float(ub.y << 16);
            uh.w = __uint_as_float(ub.y & 0xffff0000u);
            float4 alo = *(const float4*)&aL[k][0];
            float4 ahi = *(const float4*)&aL[k][4];
            fma4(o[0], alo.x, uh); fma4(o[1], alo.y, uh);
            fma4(o[2], alo.z, uh); fma4(o[3], alo.w, uh);
            fma4(o[4], ahi.x, uh); fma4(o[5], ahi.y, uh);
            fma4(o[6], ahi.z, uh); fma4(o[7], ahi.w, uh);
        }
        #pragma unroll
        for (int r = 0; r < 8; ++r)
            __builtin_nontemporal_store(*(const f32x4*)&o[r],
                                        &O4[(size_t)(r0 + r) * D4 + col]);
    }
}

// ---------------------------------------------------------------------------
// Fallback (ws too small): R5's proven scalar kernel.
// ---------------------------------------------------------------------------
__global__ __launch_bounds__(TPB) void flow_main_fb(const float* __restrict__ Xg,
                                                    const float* __restrict__ Wg,
                                                    const float* __restrict__ Ug,
                                                    const float* __restrict__ Bg,
                                                    const float* __restrict__ tbl,
                                                    float* __restrict__ Og) {
    const int t = threadIdx.x;
    const int wave = t >> 6, lane = t & 63;
    const int rowBase = blockIdx.x * ROWS;

    __shared__ __align__(16) float xs[2][ROWS][CHUNK];
    __shared__ __align__(16) float gts[NF][NF + 1];
    __shared__ __align__(16) float c0p[NF][ROWS];
    __shared__ __align__(16) float aTs[NF][ROWS];
    __shared__ float bsS[NF];
    __shared__ float coefS[NF];

    const float4* X4 = (const float4*)Xg;
    const float4* W4 = (const float4*)Wg;
    const float4* U4 = (const float4*)Ug;

    for (int e = t; e < NF * NF; e += TPB) {
        const int jj = e % NF;
        gts[e / NF][jj] = tbl[UW_OFF + e] + tbl[COEF_OFF + jj] * tbl[WW_OFF + e];
    }
    if (t < NF) { bsS[t] = Bg[t]; coefS[t] = tbl[COEF_OFF + t]; }

    const int srow = (t >> 8) * 2;
    const int sc4  = t & 255;

    float4 p0 = X4[(size_t)(rowBase + srow)     * D4 + sc4];
    float4 p1 = X4[(size_t)(rowBase + srow + 1) * D4 + sc4];
    *(float4*)&xs[0][srow][sc4 * 4]     = p0;
    *(float4*)&xs[0][srow + 1][sc4 * 4] = p1;
    __syncthreads();

    const int kt = wave & 7, rt = wave >> 3;
    const int k0 = kt * 5, r0 = rt * 4;

    float acc[4][5];
    #pragma unroll
    for (int r = 0; r < 4; ++r)
        #pragma unroll
        for (int kk = 0; kk < 5; ++kk) acc[r][kk] = 0.f;

    int b = 0;
    for (int c = 0; c < NCHUNK; ++c) {
        if (c + 1 < NCHUNK) {
            p0 = X4[(size_t)(rowBase + srow)     * D4 + (c + 1) * CH4 + sc4];
            p1 = X4[(size_t)(rowBase + srow + 1) * D4 + (c + 1) * CH4 + sc4];
        }
        #pragma unroll 1
        for (int s = 0; s < 4; ++s) {
            const int col4 = c * CH4 + s * 64 + lane;
            float4 wv[5];
            #pragma unroll
            for (int kk = 0; kk < 5; ++kk)
                wv[kk] = W4[(size_t)(k0 + kk) * D4 + col4];
            const int lc = (s * 64 + lane) * 4;
            #pragma unroll
            for (int r = 0; r < 4; ++r) {
                float4 xv = *(const float4*)&xs[b][r0 + r][lc];
                #pragma unroll
                for (int kk = 0; kk < 5; ++kk)
                    acc[r][kk] = fmaf(xv.x, wv[kk].x,
                                 fmaf(xv.y, wv[kk].y,
                                 fmaf(xv.z, wv[kk].z,
                                 fmaf(xv.w, wv[kk].w, acc[r][kk]))));
            }
        }
        if (c + 1 < NCHUNK) {
            *(float4*)&xs[b ^ 1][srow][sc4 * 4]     = p0;
            *(float4*)&xs[b ^ 1][srow + 1][sc4 * 4] = p1;
        }
        __syncthreads();
        b ^= 1;
    }

    #pragma unroll
    for (int r = 0; r < 4; ++r)
        #pragma unroll
        for (int kk = 0; kk < 5; ++kk) {
            float v = acc[r][kk];
            #pragma unroll
            for (int off = 32; off >= 1; off >>= 1) v += __shfl_xor(v, off);
            acc[r][kk] = v;
        }
    if (lane == 0) {
        #pragma unroll
        for (int kk = 0; kk < 5; ++kk)
            #pragma unroll
            for (int r = 0; r < 4; ++r)
                c0p[k0 + kk][r0 + r] = acc[r][kk];
    }
    __syncthreads();

    float4 o[ROWS];
    {
        const int col = wave * 64 + lane;
        #pragma unroll
        for (int r = 0; r < ROWS; ++r)
            o[r] = X4[(size_t)(rowBase + r) * D4 + col];
    }

    if (wave < ROWS) {
        const int r = wave, j = lane;
        float aj = 0.f;
        for (int k = 0; k < NF; ++k) {
            float gv = (j < k) ? gts[k][j] : 0.f;
            float tv = aj * gv;
            #pragma unroll
            for (int off = 32; off >= 1; off >>= 1) tv += __shfl_xor(tv, off);
            float sum = c0p[k][r] + bsS[k] + tv;
            float ak = tanhf(sum);
            if (j == k) aj = ak;
        }
        if (j < NF) aTs[j][r] = aj;
    }
    __syncthreads();

    float4* O4 = (float4*)Og;
    #pragma unroll 1
    for (int p = 0; p < 4; ++p) {
        const int col = p * 1024 + wave * 64 + lane;
        if (p > 0) {
            #pragma unroll
            for (int r = 0; r < ROWS; ++r)
                o[r] = X4[(size_t)(rowBase + r) * D4 + col];
        }
        #pragma unroll 2
        for (int k = 0; k < NF; ++k) {
            float4 uu = U4[(size_t)k * D4 + col];
            float4 wv = W4[(size_t)k * D4 + col];
            const float cf = coefS[k];
            float4 uh;
            uh.x = fmaf(cf, wv.x, uu.x);
            uh.y = fmaf(cf, wv.y, uu.y);
            uh.z = fmaf(cf, wv.z, uu.z);
            uh.w = fmaf(cf, wv.w, uu.w);
            float4 alo = *(const float4*)&aTs[k][0];
            float4 ahi = *(const float4*)&aTs[k][4];
            fma4(o[0], alo.x, uh); fma4(o[1], alo.y, uh);
            fma4(o[2], alo.z, uh); fma4(o[3], alo.w, uh);
            fma4(o[4], ahi.x, uh); fma4(o[5], ahi.y, uh);
            fma4(o[6], ahi.z, uh); fma4(o[7], ahi.w, uh);
        }
        #pragma unroll
        for (int r = 0; r < ROWS; ++r)
            O4[(size_t)(rowBase + r) * D4 + col] = o[r];
    }
}

extern "C" void kernel_launch(void* const* d_in, const int* in_sizes, int n_in,
                              void* d_out, int out_size, void* d_ws, size_t ws_size,
                              hipStream_t stream) {
    const float* X  = (const float*)d_in[0];
    const float* Wg = (const float*)d_in[1];
    const float* Ug = (const float*)d_in[2];
    const float* Bg = (const float*)d_in[3];
    float* out = (float*)d_out;
    float* tbl = (float*)d_ws;

    const bool fast = ws_size >= (size_t)WS_NEED * sizeof(float);

    if (fast) {
        pair_wb_kernel<<<NFP * 8, 512, 0, stream>>>(Wg, Ug, tbl, 1);
        gemm_part_kernel<<<(S / 16) * KSPLIT, 256, 0, stream>>>(X, tbl);
        reduce_rec_kernel<<<S / 8, 512, 0, stream>>>(Bg, tbl);
        apply_kernel<<<(S / 8) * 8, 256, 0, stream>>>(X, tbl, out);
    } else {
        pair_wb_kernel<<<NF * 8, 512, 0, stream>>>(Wg, Ug, tbl, 0);
        flow_main_fb<<<S / ROWS, TPB, 0, stream>>>(X, Wg, Ug, Bg, tbl, out);
    }
}